// Round 1
// baseline (1730.589 us; speedup 1.0000x reference)
//
#include <hip/hip_runtime.h>
#include <math.h>

#define HW 4096
#define CIN 256
#define BN_EPS 1e-5f
#define TJ 32

// ---------------------------------------------------------------------------
// 1x1 conv + folded BN + ReLU.  out layout: [b*HW + pixel][OC]  (pixel-major)
// grid = B*HW/64 = 256 blocks, 256 threads.
// thread (p = tid&63, og = tid>>6) computes OC/4 outputs for one pixel.
// ---------------------------------------------------------------------------
template <int OC>
__global__ __launch_bounds__(256) void conv_bn_relu_kernel(
    const float* __restrict__ x, const float* __restrict__ w,
    const float* __restrict__ bias, const float* __restrict__ g,
    const float* __restrict__ be, const float* __restrict__ m,
    const float* __restrict__ v, float* __restrict__ out)
{
    const int bid = blockIdx.x;
    const int b   = bid >> 6;            // batch
    const int p0  = (bid & 63) << 6;     // pixel tile base
    const int tid = threadIdx.x;
    const int p   = tid & 63;
    const int og  = tid >> 6;            // 0..3
    constexpr int OPT = OC / 4;          // outputs per thread

    __shared__ float xt[64 * 64];        // [c_chunk][px] 16 KB

    float acc[OPT];
#pragma unroll
    for (int k = 0; k < OPT; k++) acc[k] = 0.f;

    for (int c0 = 0; c0 < CIN; c0 += 64) {
        __syncthreads();
#pragma unroll
        for (int t = 0; t < 16; t++) {
            int idx = tid + t * 256;
            int cc = idx >> 6, pp = idx & 63;
            xt[idx] = x[((size_t)(b * CIN + c0 + cc) << 12) + p0 + pp];
        }
        __syncthreads();
        for (int cc = 0; cc < 64; cc += 4) {
            float x0 = xt[(cc + 0) * 64 + p];
            float x1v = xt[(cc + 1) * 64 + p];
            float x2v = xt[(cc + 2) * 64 + p];
            float x3v = xt[(cc + 3) * 64 + p];
#pragma unroll
            for (int k = 0; k < OPT; k++) {
                const float4 w4 = *(const float4*)&w[(og * OPT + k) * CIN + c0 + cc];
                acc[k] += w4.x * x0 + w4.y * x1v + w4.z * x2v + w4.w * x3v;
            }
        }
    }
#pragma unroll
    for (int k = 0; k < OPT; k++) {
        int o = og * OPT + k;
        float A  = g[o] * rsqrtf(v[o] + BN_EPS);
        float Bv = (bias[o] - m[o]) * A + be[o];
        float y  = fmaxf(acc[k] * A + Bv, 0.f);
        out[((size_t)(b * HW + p0 + p)) * OC + o] = y;
    }
}

// ---------------------------------------------------------------------------
// Flash attention: per block, one batch b and one i-tile of 64 queries.
// 512 threads: lane = i within tile (0..63), grp = tid>>6 (0..7).
// Each thread: Q row in regs (16 float4), accumulates O[i][grp*32 .. +31].
// Online softmax state (m,l) replicated across the 8 grp-threads of a row.
// Epilogue: out = gam * O/l + x1   (residual), layout (B,C,H,W).
// ---------------------------------------------------------------------------
__global__ __launch_bounds__(512) void flash_attn_kernel(
    const float* __restrict__ Q, const float* __restrict__ K,
    const float* __restrict__ V, const float* __restrict__ x1,
    const float* __restrict__ gam, float* __restrict__ out)
{
    const int bid  = blockIdx.x;
    const int b    = bid >> 6;
    const int i0   = (bid & 63) << 6;
    const int tid  = threadIdx.x;
    const int lane = tid & 63;   // query index within tile
    const int grp  = tid >> 6;   // 0..7

    __shared__ float Klds[TJ * 68];    // [jj][d], pad 64->68 (row 16B-aligned)
    __shared__ float Vlds[TJ * 256];   // [jj][c]
    __shared__ float Plds[64 * 33];    // [i][jj], pad 32->33 (2-way = free)
    __shared__ float red_max[8 * 64];
    __shared__ float red_sum[8 * 64];

    // Q row -> registers (64 floats)
    float4 qreg[16];
    {
        const float4* qrow = (const float4*)(Q + ((size_t)(b * HW + i0 + lane) << 6));
#pragma unroll
        for (int t = 0; t < 16; t++) qreg[t] = qrow[t];
    }

    float4 acc[8];
#pragma unroll
    for (int t = 0; t < 8; t++) acc[t] = make_float4(0.f, 0.f, 0.f, 0.f);
    float m_run = -1e30f, l_run = 0.f;

    const float4* Vg = (const float4*)(V + ((size_t)(b * HW) << 8));
    const float4* Kg = (const float4*)(K + ((size_t)(b * HW) << 6));

    for (int j0 = 0; j0 < HW; j0 += TJ) {
        __syncthreads();
        // stage K tile: 32 rows x 16 float4 = 512
        if (tid < 512) {
            int jj = tid >> 4, d4 = tid & 15;
            float4 kv = Kg[(size_t)(j0 + jj) * 16 + d4];
            *(float4*)&Klds[jj * 68 + d4 * 4] = kv;
        }
        // stage V tile: 32 rows x 64 float4 = 2048 -> 4 per thread
#pragma unroll
        for (int t = 0; t < 4; t++) {
            int idx = tid + t * 512;
            int jj = idx >> 6, c4 = idx & 63;
            *(float4*)&Vlds[jj * 256 + c4 * 4] = Vg[(size_t)(j0 + jj) * 64 + c4];
        }
        __syncthreads();

        // scores: thread computes j = grp*4 + jj, jj in 0..3 (no sqrt(d) scale in ref)
        float s[4] = {0.f, 0.f, 0.f, 0.f};
#pragma unroll
        for (int d4 = 0; d4 < 16; d4++) {
            float4 q = qreg[d4];
#pragma unroll
            for (int jj = 0; jj < 4; jj++) {
                const float4 kv = *(const float4*)&Klds[(grp * 4 + jj) * 68 + d4 * 4];
                s[jj] += q.x * kv.x + q.y * kv.y + q.z * kv.z + q.w * kv.w;
            }
        }
        float pm = fmaxf(fmaxf(s[0], s[1]), fmaxf(s[2], s[3]));
        red_max[grp * 64 + lane] = pm;
        __syncthreads();

        float mt = red_max[lane];
#pragma unroll
        for (int g2 = 1; g2 < 8; g2++) mt = fmaxf(mt, red_max[g2 * 64 + lane]);
        float m_new = fmaxf(m_run, mt);

        float ps = 0.f;
#pragma unroll
        for (int jj = 0; jj < 4; jj++) {
            float pv = __expf(s[jj] - m_new);
            ps += pv;
            Plds[lane * 33 + grp * 4 + jj] = pv;
        }
        red_sum[grp * 64 + lane] = ps;
        __syncthreads();

        float rs = red_sum[lane];
#pragma unroll
        for (int g2 = 1; g2 < 8; g2++) rs += red_sum[g2 * 64 + lane];
        float alpha = __expf(m_run - m_new);   // first iter: exp(-inf) = 0, safe
        l_run = l_run * alpha + rs;
        m_run = m_new;
#pragma unroll
        for (int t = 0; t < 8; t++) {
            acc[t].x *= alpha; acc[t].y *= alpha;
            acc[t].z *= alpha; acc[t].w *= alpha;
        }

        // PV: O[i][grp*32 + :] += P[i][jj] * V[jj][grp*32 + :]
        for (int jj = 0; jj < TJ; jj++) {
            float pv = Plds[lane * 33 + jj];
            const float4* vrow = (const float4*)&Vlds[jj * 256 + grp * 32];
#pragma unroll
            for (int k4 = 0; k4 < 8; k4++) {
                float4 vv = vrow[k4];
                acc[k4].x += pv * vv.x; acc[k4].y += pv * vv.y;
                acc[k4].z += pv * vv.z; acc[k4].w += pv * vv.w;
            }
        }
    }

    // epilogue: out[b][c][i] = gam * O/l + x1[b][c][i]
    float invl = 1.0f / l_run;
    float gv = gam[0];
#pragma unroll
    for (int k4 = 0; k4 < 8; k4++) {
        int cb = grp * 32 + k4 * 4;
        float vals[4] = {acc[k4].x, acc[k4].y, acc[k4].z, acc[k4].w};
#pragma unroll
        for (int cc = 0; cc < 4; cc++) {
            size_t idx = ((size_t)(b * CIN + cb + cc) << 12) + i0 + lane;
            out[idx] = gv * (vals[cc] * invl) + x1[idx];
        }
    }
}

// ---------------------------------------------------------------------------
extern "C" void kernel_launch(void* const* d_in, const int* in_sizes, int n_in,
                              void* d_out, int out_size, void* d_ws, size_t ws_size,
                              hipStream_t stream)
{
    const float* x1  = (const float*)d_in[0];
    const float* x2  = (const float*)d_in[1];
    const float* x3  = (const float*)d_in[2];
    const float* w1  = (const float*)d_in[3];
    const float* b1  = (const float*)d_in[4];
    const float* g1  = (const float*)d_in[5];
    const float* be1 = (const float*)d_in[6];
    const float* m1  = (const float*)d_in[7];
    const float* v1  = (const float*)d_in[8];
    const float* w2  = (const float*)d_in[9];
    const float* b2  = (const float*)d_in[10];
    const float* g2  = (const float*)d_in[11];
    const float* be2 = (const float*)d_in[12];
    const float* m2  = (const float*)d_in[13];
    const float* v2  = (const float*)d_in[14];
    const float* w3  = (const float*)d_in[15];
    const float* b3  = (const float*)d_in[16];
    const float* g3  = (const float*)d_in[17];
    const float* be3 = (const float*)d_in[18];
    const float* m3  = (const float*)d_in[19];
    const float* v3  = (const float*)d_in[20];
    const float* gam = (const float*)d_in[21];

    float* ws = (float*)d_ws;
    float* Qw = ws;                       //  4 MB: [b*HW + i][64]
    float* Kw = ws + (1 << 20);           //  4 MB: [b*HW + j][64]
    float* Vw = ws + (2 << 20);           // 16 MB: [b*HW + j][256]

    conv_bn_relu_kernel<64><<<256, 256, 0, stream>>>(x1, w1, b1, g1, be1, m1, v1, Qw);
    conv_bn_relu_kernel<64><<<256, 256, 0, stream>>>(x2, w2, b2, g2, be2, m2, v2, Kw);
    conv_bn_relu_kernel<256><<<256, 256, 0, stream>>>(x3, w3, b3, g3, be3, m3, v3, Vw);
    flash_attn_kernel<<<256, 512, 0, stream>>>(Qw, Kw, Vw, x1, gam, (float*)d_out);
}

// Round 2
// 616.561 us; speedup vs baseline: 2.8068x; 2.8068x over previous
//
#include <hip/hip_runtime.h>
#include <math.h>

#define HW 4096
#define CIN 256
#define BN_EPS 1e-5f
#define LOG2E 1.44269504088896f

typedef __attribute__((ext_vector_type(8))) short short8;
typedef __attribute__((ext_vector_type(4))) float floatx4;
typedef unsigned short ushort;

__device__ inline ushort f2bf(float f) {
    union { float f; unsigned u; } c; c.f = f;
    unsigned r = c.u + 0x7fff + ((c.u >> 16) & 1);   // RNE; inputs are finite
    return (ushort)(r >> 16);
}

// ---------------------------------------------------------------------------
// conv+BN+ReLU -> bf16, OC=64, out layout [b][pixel][64] (row-major d).
// scale folds log2(e) into Q so softmax can use native exp2.
// ---------------------------------------------------------------------------
__global__ __launch_bounds__(256) void conv_qk_kernel(
    const float* __restrict__ x, const float* __restrict__ w,
    const float* __restrict__ bias, const float* __restrict__ g,
    const float* __restrict__ be, const float* __restrict__ m,
    const float* __restrict__ v, float scale, ushort* __restrict__ out)
{
    const int bid = blockIdx.x;
    const int b   = bid >> 6;
    const int p0  = (bid & 63) << 6;
    const int tid = threadIdx.x;
    const int p   = tid & 63;
    const int og  = tid >> 6;            // 0..3 -> oc 16*og..

    __shared__ float xt[64 * 64];

    float acc[16];
#pragma unroll
    for (int k = 0; k < 16; k++) acc[k] = 0.f;

    for (int c0 = 0; c0 < CIN; c0 += 64) {
        __syncthreads();
#pragma unroll
        for (int t = 0; t < 16; t++) {
            int idx = tid + t * 256;
            int cc = idx >> 6, pp = idx & 63;
            xt[idx] = x[((size_t)(b * CIN + c0 + cc) << 12) + p0 + pp];
        }
        __syncthreads();
        for (int cc = 0; cc < 64; cc += 4) {
            float x0 = xt[(cc + 0) * 64 + p];
            float x1 = xt[(cc + 1) * 64 + p];
            float x2 = xt[(cc + 2) * 64 + p];
            float x3 = xt[(cc + 3) * 64 + p];
#pragma unroll
            for (int k = 0; k < 16; k++) {
                const float4 w4 = *(const float4*)&w[(og * 16 + k) * CIN + c0 + cc];
                acc[k] += w4.x * x0 + w4.y * x1 + w4.z * x2 + w4.w * x3;
            }
        }
    }
    alignas(16) ushort vals[16];
#pragma unroll
    for (int k = 0; k < 16; k++) {
        int o = og * 16 + k;
        float A  = g[o] * rsqrtf(v[o] + BN_EPS);
        float Bv = (bias[o] - m[o]) * A + be[o];
        vals[k] = f2bf(fmaxf(acc[k] * A + Bv, 0.f) * scale);
    }
    size_t base = ((size_t)(b * HW + p0 + p)) * 64 + og * 16;
    *(short8*)&out[base]     = *(short8*)&vals[0];
    *(short8*)&out[base + 8] = *(short8*)&vals[8];
}

// ---------------------------------------------------------------------------
// conv+BN+ReLU -> bf16, OC=256, out layout [b][c][pixel] (V transposed).
// ---------------------------------------------------------------------------
__global__ __launch_bounds__(256) void conv_v_kernel(
    const float* __restrict__ x, const float* __restrict__ w,
    const float* __restrict__ bias, const float* __restrict__ g,
    const float* __restrict__ be, const float* __restrict__ m,
    const float* __restrict__ v, ushort* __restrict__ out)
{
    const int bid = blockIdx.x;
    const int b   = bid >> 6;
    const int p0  = (bid & 63) << 6;
    const int tid = threadIdx.x;
    const int p   = tid & 63;
    const int og  = tid >> 6;            // 0..3 -> oc 64*og..

    __shared__ float xt[64 * 64];

    float acc[64];
#pragma unroll
    for (int k = 0; k < 64; k++) acc[k] = 0.f;

    for (int c0 = 0; c0 < CIN; c0 += 64) {
        __syncthreads();
#pragma unroll
        for (int t = 0; t < 16; t++) {
            int idx = tid + t * 256;
            int cc = idx >> 6, pp = idx & 63;
            xt[idx] = x[((size_t)(b * CIN + c0 + cc) << 12) + p0 + pp];
        }
        __syncthreads();
        for (int cc = 0; cc < 64; cc += 4) {
            float x0 = xt[(cc + 0) * 64 + p];
            float x1 = xt[(cc + 1) * 64 + p];
            float x2 = xt[(cc + 2) * 64 + p];
            float x3 = xt[(cc + 3) * 64 + p];
#pragma unroll
            for (int k = 0; k < 64; k++) {
                const float4 w4 = *(const float4*)&w[(og * 64 + k) * CIN + c0 + cc];
                acc[k] += w4.x * x0 + w4.y * x1 + w4.z * x2 + w4.w * x3;
            }
        }
    }
#pragma unroll
    for (int k = 0; k < 64; k++) {
        int o = og * 64 + k;
        float A  = g[o] * rsqrtf(v[o] + BN_EPS);
        float Bv = (bias[o] - m[o]) * A + be[o];
        float y  = fmaxf(acc[k] * A + Bv, 0.f);
        out[((size_t)(b * CIN + o) << 12) + p0 + p] = f2bf(y);
    }
}

// ---------------------------------------------------------------------------
// MFMA flash attention. Block: 512 thr = 8 waves; wave (wr = w&1, wc = w>>1).
// TI=64 queries (i0), TJ=64 keys per iter. Wave computes:
//   S rows 32*wr..+32 (2 i-tiles), j-cols 16*wc..+16  (4 MFMAs)
//   O^T c-rows 64*wc..+64 (4 m-tiles), i-cols 32*wr..+32 (16 MFMAs)
// l (softmax denom) = extra ones-row of V -> rides in MFMA accumulator.
// Q pre-scaled by log2e so exp == exp2 (v_exp_f32 native).
// ---------------------------------------------------------------------------
__global__ __launch_bounds__(512) void flash_mfma(
    const ushort* __restrict__ Q, const ushort* __restrict__ K,
    const ushort* __restrict__ Vt, const float* __restrict__ x1,
    const float* __restrict__ gam, float* __restrict__ out)
{
    const int tid  = threadIdx.x;
    const int lane = tid & 63;
    const int wv   = tid >> 6;
    const int wr   = wv & 1, wc = wv >> 1;
    const int l15  = lane & 15, qd = lane >> 4;

    // XCD swizzle: XCD x serves batch x>>1 -> per-XCD L2 holds one batch's K+V
    const int bid   = blockIdx.x;
    const int b     = (bid & 7) >> 1;
    const int itile = ((bid >> 3) << 1) | (bid & 1);
    const int i0    = itile << 6;

    __shared__ alignas(16) ushort Kt[64 * 72];          // [j][d], pad->72
    __shared__ alignas(16) ushort Vtl[272 * 72];        // [c][j]; rows 256..271: ones-row + zeros
    __shared__ alignas(16) ushort Pt[64 * 72];          // [i][j] bf16
    __shared__ alignas(16) float  redm[4][64];          // per-wc partial row max
    __shared__ float lrow[64];

    // ones-row init (rows 256..271 of Vtl persist across the whole loop)
    for (int idx = tid; idx < 16 * 72; idx += 512) {
        int rr = idx / 72;
        Vtl[256 * 72 + idx] = (rr == 0) ? (ushort)0x3F80 : (ushort)0;
    }

    // Q A-fragments in registers: A[m=i][k=d], m = 32wr+16it+l15, k = 32kb+8qd+j
    short8 qf[2][2];
#pragma unroll
    for (int it = 0; it < 2; it++)
#pragma unroll
        for (int kb = 0; kb < 2; kb++)
            qf[it][kb] = *(const short8*)(Q +
                (((size_t)(b * HW + i0 + 32 * wr + 16 * it + l15)) << 6) + kb * 32 + qd * 8);

    const floatx4 zv = {0.f, 0.f, 0.f, 0.f};
    floatx4 oa[4][2];
#pragma unroll
    for (int mt = 0; mt < 4; mt++) { oa[mt][0] = zv; oa[mt][1] = zv; }
    floatx4 oa_l[2] = {zv, zv};                          // l-tile (wc==3 only)
    float m_q[2][4], m_l[2];
#pragma unroll
    for (int it = 0; it < 2; it++) {
        m_l[it] = -3.0e38f;
#pragma unroll
        for (int r = 0; r < 4; r++) m_q[it][r] = -3.0e38f;
    }

    for (int j0 = 0; j0 < HW; j0 += 64) {
        __syncthreads();                                  // prev iter's LDS reads done
        {
            int row = tid >> 3, c16 = tid & 7;            // K: 64 rows x 8 x16B
            *(short8*)&Kt[row * 72 + c16 * 8] =
                *(const short8*)(K + (((size_t)(b * HW + j0 + row)) << 6) + c16 * 8);
#pragma unroll
            for (int t2 = 0; t2 < 4; t2++) {              // V: 256 rows x 8 x16B
                int idx = tid + (t2 << 9);
                int vr = idx >> 3, vc = idx & 7;
                *(short8*)&Vtl[vr * 72 + vc * 8] =
                    *(const short8*)(Vt + (((size_t)(b * CIN + vr)) << 12) + j0 + vc * 8);
            }
        }
        __syncthreads();

        // ---- S = Q K^T : B-frag from Kt[j=16wc+l15][d]
        floatx4 s0 = zv, s1 = zv;
#pragma unroll
        for (int kb = 0; kb < 2; kb++) {
            short8 kf = *(short8*)&Kt[(16 * wc + l15) * 72 + kb * 32 + qd * 8];
            s0 = __builtin_amdgcn_mfma_f32_16x16x32_bf16(qf[0][kb], kf, s0, 0, 0, 0);
            s1 = __builtin_amdgcn_mfma_f32_16x16x32_bf16(qf[1][kb], kf, s1, 0, 0, 0);
        }
        float sv[2][4] = {{s0[0], s0[1], s0[2], s0[3]}, {s1[0], s1[1], s1[2], s1[3]}};

        // ---- partial row max over this wave's 16 j (butterfly within 16 lanes)
        float pm[2][4];
#pragma unroll
        for (int it = 0; it < 2; it++)
#pragma unroll
            for (int r = 0; r < 4; r++) {
                float vx = sv[it][r];
                vx = fmaxf(vx, __shfl_xor(vx, 1));
                vx = fmaxf(vx, __shfl_xor(vx, 2));
                vx = fmaxf(vx, __shfl_xor(vx, 4));
                vx = fmaxf(vx, __shfl_xor(vx, 8));
                pm[it][r] = vx;
            }
        if (l15 == 0) {
#pragma unroll
            for (int it = 0; it < 2; it++)
                *(float4*)&redm[wc][32 * wr + 16 * it + 4 * qd] =
                    make_float4(pm[it][0], pm[it][1], pm[it][2], pm[it][3]);
        }
        __syncthreads();

        // ---- combine max across the 4 wc partials
        float mn_q[2][4], mn_l[2];
#pragma unroll
        for (int it = 0; it < 2; it++) {
            int rq = 32 * wr + 16 * it + 4 * qd;
            float4 a0 = *(float4*)&redm[0][rq];
            float4 a1 = *(float4*)&redm[1][rq];
            float4 a2 = *(float4*)&redm[2][rq];
            float4 a3 = *(float4*)&redm[3][rq];
            mn_q[it][0] = fmaxf(m_q[it][0], fmaxf(fmaxf(a0.x, a1.x), fmaxf(a2.x, a3.x)));
            mn_q[it][1] = fmaxf(m_q[it][1], fmaxf(fmaxf(a0.y, a1.y), fmaxf(a2.y, a3.y)));
            mn_q[it][2] = fmaxf(m_q[it][2], fmaxf(fmaxf(a0.z, a1.z), fmaxf(a2.z, a3.z)));
            mn_q[it][3] = fmaxf(m_q[it][3], fmaxf(fmaxf(a0.w, a1.w), fmaxf(a2.w, a3.w)));
            int rl = 32 * wr + 16 * it + l15;
            mn_l[it] = fmaxf(m_l[it],
                fmaxf(fmaxf(redm[0][rl], redm[1][rl]), fmaxf(redm[2][rl], redm[3][rl])));
        }

        // ---- P = exp2(S - m) -> bf16 -> LDS (C-layout write, A/B-layout read)
#pragma unroll
        for (int it = 0; it < 2; it++)
#pragma unroll
            for (int r = 0; r < 4; r++) {
                float p = exp2f(sv[it][r] - mn_q[it][r]);
                Pt[(32 * wr + 16 * it + 4 * qd + r) * 72 + 16 * wc + l15] = f2bf(p);
                m_q[it][r] = mn_q[it][r];
            }
        __syncthreads();

        // ---- rescale (skip when max unchanged, wave vote)
        float alpha[2];
#pragma unroll
        for (int it = 0; it < 2; it++) {
            alpha[it] = exp2f(m_l[it] - mn_l[it]);
            m_l[it] = mn_l[it];
        }
        if (__any(fminf(alpha[0], alpha[1]) < 1.0f)) {
#pragma unroll
            for (int mt = 0; mt < 4; mt++) {
                oa[mt][0] *= alpha[0];
                oa[mt][1] *= alpha[1];
            }
            oa_l[0] *= alpha[0];
            oa_l[1] *= alpha[1];
        }

        // ---- O^T += V^T P^T : A-frag = Vt rows (c), B-frag = Pt rows (i)
#pragma unroll
        for (int kb = 0; kb < 2; kb++) {
            short8 pf0 = *(short8*)&Pt[(32 * wr + l15) * 72 + kb * 32 + qd * 8];
            short8 pf1 = *(short8*)&Pt[(32 * wr + 16 + l15) * 72 + kb * 32 + qd * 8];
#pragma unroll
            for (int mt = 0; mt < 4; mt++) {
                short8 vf = *(short8*)&Vtl[(64 * wc + 16 * mt + l15) * 72 + kb * 32 + qd * 8];
                oa[mt][0] = __builtin_amdgcn_mfma_f32_16x16x32_bf16(vf, pf0, oa[mt][0], 0, 0, 0);
                oa[mt][1] = __builtin_amdgcn_mfma_f32_16x16x32_bf16(vf, pf1, oa[mt][1], 0, 0, 0);
            }
            if (wc == 3) {                                // ones-row tile -> l
                short8 vf = *(short8*)&Vtl[(256 + l15) * 72 + kb * 32 + qd * 8];
                oa_l[0] = __builtin_amdgcn_mfma_f32_16x16x32_bf16(vf, pf0, oa_l[0], 0, 0, 0);
                oa_l[1] = __builtin_amdgcn_mfma_f32_16x16x32_bf16(vf, pf1, oa_l[1], 0, 0, 0);
            }
        }
    }

    // ---- broadcast l, epilogue: out = gam*O/l + x1
    __syncthreads();
    if (wc == 3 && qd == 0) {
        lrow[32 * wr + l15]      = oa_l[0][0];
        lrow[32 * wr + 16 + l15] = oa_l[1][0];
    }
    __syncthreads();

    const float gv = gam[0];
#pragma unroll
    for (int it = 0; it < 2; it++) {
        int i = 32 * wr + 16 * it + l15;
        float il = gv / lrow[i];
#pragma unroll
        for (int mt = 0; mt < 4; mt++)
#pragma unroll
            for (int r = 0; r < 4; r++) {
                int c = 64 * wc + 16 * mt + 4 * qd + r;
                size_t idx = (((size_t)(b * CIN + c)) << 12) + i0 + i;
                out[idx] = oa[mt][it][r] * il + x1[idx];
            }
    }
}

// ---------------------------------------------------------------------------
extern "C" void kernel_launch(void* const* d_in, const int* in_sizes, int n_in,
                              void* d_out, int out_size, void* d_ws, size_t ws_size,
                              hipStream_t stream)
{
    const float* x1  = (const float*)d_in[0];
    const float* x2  = (const float*)d_in[1];
    const float* x3  = (const float*)d_in[2];
    const float* w1  = (const float*)d_in[3];
    const float* b1  = (const float*)d_in[4];
    const float* g1  = (const float*)d_in[5];
    const float* be1 = (const float*)d_in[6];
    const float* m1  = (const float*)d_in[7];
    const float* v1  = (const float*)d_in[8];
    const float* w2  = (const float*)d_in[9];
    const float* b2  = (const float*)d_in[10];
    const float* g2  = (const float*)d_in[11];
    const float* be2 = (const float*)d_in[12];
    const float* m2  = (const float*)d_in[13];
    const float* v2  = (const float*)d_in[14];
    const float* w3  = (const float*)d_in[15];
    const float* b3  = (const float*)d_in[16];
    const float* g3  = (const float*)d_in[17];
    const float* be3 = (const float*)d_in[18];
    const float* m3  = (const float*)d_in[19];
    const float* v3  = (const float*)d_in[20];
    const float* gam = (const float*)d_in[21];

    ushort* Qw = (ushort*)d_ws;                 // [b][i][64]   2 MB
    ushort* Kw = Qw + (size_t)4 * HW * 64;      // [b][j][64]   2 MB
    ushort* Vw = Kw + (size_t)4 * HW * 64;      // [b][c][j]    8 MB

    conv_qk_kernel<<<256, 256, 0, stream>>>(x1, w1, b1, g1, be1, m1, v1, LOG2E, Qw);
    conv_qk_kernel<<<256, 256, 0, stream>>>(x2, w2, b2, g2, be2, m2, v2, 1.0f, Kw);
    conv_v_kernel <<<256, 256, 0, stream>>>(x3, w3, b3, g3, be3, m3, v3, Vw);
    flash_mfma    <<<256, 512, 0, stream>>>(Qw, Kw, Vw, x1, gam, (float*)d_out);
}

// Round 3
// 338.756 us; speedup vs baseline: 5.1087x; 1.8201x over previous
//
#include <hip/hip_runtime.h>
#include <math.h>

#define HW 4096
#define CIN 256
#define BN_EPS 1e-5f
#define LOG2E 1.44269504088896f

typedef __attribute__((ext_vector_type(8))) short short8;
typedef __attribute__((ext_vector_type(4))) float floatx4;
typedef __attribute__((ext_vector_type(4))) unsigned short u16x4;
typedef unsigned short ushort;
typedef unsigned int u32;

__device__ inline ushort f2bf(float f) {
    union { float f; unsigned u; } c; c.f = f;
    unsigned r = c.u + 0x7fff + ((c.u >> 16) & 1);   // RNE; inputs are finite
    return (ushort)(r >> 16);
}

// async global->LDS, 16B per lane. LDS dest must be wave-uniform base + lane*16.
__device__ inline void load_lds16(const ushort* g, ushort* l) {
    __builtin_amdgcn_global_load_lds(
        (const __attribute__((address_space(1))) u32*)g,
        (__attribute__((address_space(3))) u32*)l, 16, 0, 0);
}

// ---------------------------------------------------------------------------
// x (fp32, [b][c][hw]) -> Xt (bf16, [b][hw][c])  for all three inputs.
// grid (hw/64, c/64, 12): z = input*4 + b. Classic LDS transpose, 64x64 tile.
// ---------------------------------------------------------------------------
__global__ __launch_bounds__(256) void transpose_bf16(
    const float* __restrict__ x1, const float* __restrict__ x2,
    const float* __restrict__ x3, ushort* __restrict__ Xt1,
    ushort* __restrict__ Xt2, ushort* __restrict__ Xt3)
{
    const int z = blockIdx.z;
    const int inp = z >> 2, b = z & 3;
    const float* x = inp == 0 ? x1 : (inp == 1 ? x2 : x3);
    ushort* o = inp == 0 ? Xt1 : (inp == 1 ? Xt2 : Xt3);
    const int c0 = blockIdx.y << 6, p0 = blockIdx.x << 6;
    const int tid = threadIdx.x;

    __shared__ float t[64 * 65];

    const int col = tid & 63, r4 = tid >> 6;
#pragma unroll
    for (int t2 = 0; t2 < 16; t2++) {
        int row = (t2 << 2) + r4;
        t[row * 65 + col] = x[((size_t)(b * CIN + c0 + row) << 12) + p0 + col];
    }
    __syncthreads();
    const int p = tid >> 2, cs = (tid & 3) << 4;
    alignas(16) ushort v[16];
#pragma unroll
    for (int k = 0; k < 16; k++) v[k] = f2bf(t[(cs + k) * 65 + p]);
    size_t base = ((size_t)(b * HW + p0 + p)) * 256 + c0 + cs;
    *(short8*)&o[base]     = *(short8*)&v[0];
    *(short8*)&o[base + 8] = *(short8*)&v[8];
}

// ---------------------------------------------------------------------------
// Fold BN into weights/bias, cast weights to bf16.  Q gets log2(e) folded in.
// grid 385 x 256: blocks 0..383 convert [w1|w2|w3] (96K elems), block 384 bias.
// bc layout: [0..63]=bias1, [64..127]=bias2, [128..383]=bias3
// ---------------------------------------------------------------------------
__global__ __launch_bounds__(256) void prep_weights(
    const float* __restrict__ w1, const float* __restrict__ b1,
    const float* __restrict__ g1, const float* __restrict__ be1,
    const float* __restrict__ m1, const float* __restrict__ v1,
    const float* __restrict__ w2, const float* __restrict__ b2,
    const float* __restrict__ g2, const float* __restrict__ be2,
    const float* __restrict__ m2, const float* __restrict__ v2,
    const float* __restrict__ w3, const float* __restrict__ b3,
    const float* __restrict__ g3, const float* __restrict__ be3,
    const float* __restrict__ m3, const float* __restrict__ v3,
    ushort* __restrict__ w1c, ushort* __restrict__ w2c, ushort* __restrict__ w3c,
    float* __restrict__ bc)
{
    const int bid = blockIdx.x, tid = threadIdx.x;
    if (bid < 384) {
        int idx = bid * 256 + tid;
        if (idx < 16384) {
            int o = idx >> 8;
            float A = g1[o] * rsqrtf(v1[o] + BN_EPS) * LOG2E;
            w1c[idx] = f2bf(w1[idx] * A);
        } else if (idx < 32768) {
            int i2 = idx - 16384, o = i2 >> 8;
            float A = g2[o] * rsqrtf(v2[o] + BN_EPS);
            w2c[i2] = f2bf(w2[i2] * A);
        } else {
            int i3 = idx - 32768, o = i3 >> 8;
            float A = g3[o] * rsqrtf(v3[o] + BN_EPS);
            w3c[i3] = f2bf(w3[i3] * A);
        }
    } else {
        if (tid < 64) {
            float A = g1[tid] * rsqrtf(v1[tid] + BN_EPS);
            bc[tid] = ((b1[tid] - m1[tid]) * A + be1[tid]) * LOG2E;
        } else if (tid < 128) {
            int o = tid - 64;
            float A = g2[o] * rsqrtf(v2[o] + BN_EPS);
            bc[tid] = (b2[o] - m2[o]) * A + be2[o];
        } else {
#pragma unroll
            for (int t = 0; t < 2; t++) {
                int o = (tid - 128) + t * 128;
                float A = g3[o] * rsqrtf(v3[o] + BN_EPS);
                bc[128 + o] = (b3[o] - m3[o]) * A + be3[o];
            }
        }
    }
}

// ---------------------------------------------------------------------------
// Q/K conv GEMM: out[px][oc] = relu(Xt[px][:] . W[oc][:] + bias[oc]).
// A = W (m=oc, 64), B = Xt (n=px, 128/blk), BK=64, 4 K-iters. 256 thr = 4 waves,
// wave owns n-slice of 32. XOR-swizzled LDS (global_load_lds forbids padding).
// grid (32, 4, 2): z selects Q vs K.
// ---------------------------------------------------------------------------
__global__ __launch_bounds__(256) void gemm_qk(
    const ushort* __restrict__ Xt1, const ushort* __restrict__ Xt2,
    const ushort* __restrict__ w1c, const ushort* __restrict__ w2c,
    const float* __restrict__ bc, ushort* __restrict__ Qw, ushort* __restrict__ Kw)
{
    const int which = blockIdx.z;
    const ushort* X = which ? Xt2 : Xt1;
    const ushort* W = which ? w2c : w1c;
    const float* bias = bc + which * 64;
    ushort* out = which ? Kw : Qw;
    const int b = blockIdx.y;
    const int px0 = blockIdx.x << 7;

    __shared__ alignas(16) ushort Wl[64 * 64];
    __shared__ alignas(16) ushort Xl[128 * 64];

    const int tid = threadIdx.x;
    const int lane = tid & 63;
    const int wv = tid >> 6;
    const int l15 = lane & 15, qd = lane >> 4;
    const int n0w = wv << 5;

    floatx4 acc[4][2];
#pragma unroll
    for (int mt = 0; mt < 4; mt++)
#pragma unroll
        for (int nt = 0; nt < 2; nt++) acc[mt][nt] = (floatx4){0.f, 0.f, 0.f, 0.f};

    for (int kk = 0; kk < 4; kk++) {
        const int k0 = kk << 6;
        __syncthreads();
#pragma unroll
        for (int t = 0; t < 2; t++) {            // W: 64 rows x 128B
            int L = t * 256 + tid;
            int row = L >> 3, c = L & 7;
            load_lds16(W + row * 256 + k0 + ((c ^ (row & 7)) << 3), Wl + L * 8);
        }
#pragma unroll
        for (int t = 0; t < 4; t++) {            // X: 128 rows x 128B
            int L = t * 256 + tid;
            int row = L >> 3, c = L & 7;
            load_lds16(X + ((size_t)(b * HW + px0 + row)) * 256 + k0 + ((c ^ (row & 7)) << 3),
                       Xl + L * 8);
        }
        __syncthreads();
#pragma unroll
        for (int kb = 0; kb < 2; kb++) {
            short8 af[4], bfr[2];
#pragma unroll
            for (int mt = 0; mt < 4; mt++) {
                int r = (mt << 4) + l15;
                af[mt] = *(const short8*)&Wl[(r << 6) + ((((kb << 2) + qd) ^ (r & 7)) << 3)];
            }
#pragma unroll
            for (int nt = 0; nt < 2; nt++) {
                int r = n0w + (nt << 4) + l15;
                bfr[nt] = *(const short8*)&Xl[(r << 6) + ((((kb << 2) + qd) ^ (r & 7)) << 3)];
            }
#pragma unroll
            for (int mt = 0; mt < 4; mt++)
#pragma unroll
                for (int nt = 0; nt < 2; nt++)
                    acc[mt][nt] = __builtin_amdgcn_mfma_f32_16x16x32_bf16(
                        af[mt], bfr[nt], acc[mt][nt], 0, 0, 0);
        }
    }
    // epilogue: C col(l15)=px, row(qd*4+r)=oc; pack 4 consecutive oc -> 8B store
#pragma unroll
    for (int nt = 0; nt < 2; nt++) {
        int px = px0 + n0w + (nt << 4) + l15;
#pragma unroll
        for (int mt = 0; mt < 4; mt++) {
            alignas(8) ushort v4[4];
#pragma unroll
            for (int r = 0; r < 4; r++) {
                int oc = (mt << 4) + (qd << 2) + r;
                v4[r] = f2bf(fmaxf(acc[mt][nt][r] + bias[oc], 0.f));
            }
            *(u16x4*)&out[(((size_t)(b * HW + px)) << 6) + (mt << 4) + (qd << 2)] = *(u16x4*)v4;
        }
    }
}

// ---------------------------------------------------------------------------
// V conv GEMM: out[oc][px] = relu(Xt[px][:] . W[oc][:] + bias[oc]), transposed
// store. A = Xt (m=px, 128), B = W (n=oc, 128), BK=64. 4 waves in 2x2.
// grid (32, 4, 2): z = oc-tile.
// ---------------------------------------------------------------------------
__global__ __launch_bounds__(256) void gemm_v(
    const ushort* __restrict__ Xt3, const ushort* __restrict__ w3c,
    const float* __restrict__ bc, ushort* __restrict__ Vw)
{
    const int b = blockIdx.y;
    const int px0 = blockIdx.x << 7;
    const int oc0 = blockIdx.z << 7;
    const float* bias = bc + 128;

    __shared__ alignas(16) ushort Xl[128 * 64];
    __shared__ alignas(16) ushort Wl[128 * 64];

    const int tid = threadIdx.x;
    const int lane = tid & 63;
    const int wv = tid >> 6;
    const int l15 = lane & 15, qd = lane >> 4;
    const int wm0 = (wv & 1) << 6, wn0 = (wv >> 1) << 6;

    floatx4 acc[4][4];
#pragma unroll
    for (int mt = 0; mt < 4; mt++)
#pragma unroll
        for (int nt = 0; nt < 4; nt++) acc[mt][nt] = (floatx4){0.f, 0.f, 0.f, 0.f};

    for (int kk = 0; kk < 4; kk++) {
        const int k0 = kk << 6;
        __syncthreads();
#pragma unroll
        for (int t = 0; t < 4; t++) {
            int L = t * 256 + tid;
            int row = L >> 3, c = L & 7;
            load_lds16(Xt3 + ((size_t)(b * HW + px0 + row)) * 256 + k0 + ((c ^ (row & 7)) << 3),
                       Xl + L * 8);
            load_lds16(w3c + (oc0 + row) * 256 + k0 + ((c ^ (row & 7)) << 3), Wl + L * 8);
        }
        __syncthreads();
#pragma unroll
        for (int kb = 0; kb < 2; kb++) {
            short8 af[4], bfr[4];
#pragma unroll
            for (int mt = 0; mt < 4; mt++) {
                int r = wm0 + (mt << 4) + l15;
                af[mt] = *(const short8*)&Xl[(r << 6) + ((((kb << 2) + qd) ^ (r & 7)) << 3)];
            }
#pragma unroll
            for (int nt = 0; nt < 4; nt++) {
                int r = wn0 + (nt << 4) + l15;
                bfr[nt] = *(const short8*)&Wl[(r << 6) + ((((kb << 2) + qd) ^ (r & 7)) << 3)];
            }
#pragma unroll
            for (int mt = 0; mt < 4; mt++)
#pragma unroll
                for (int nt = 0; nt < 4; nt++)
                    acc[mt][nt] = __builtin_amdgcn_mfma_f32_16x16x32_bf16(
                        af[mt], bfr[nt], acc[mt][nt], 0, 0, 0);
        }
    }
    // epilogue: col(l15)=oc, row(qd*4+r)=px; pack 4 consecutive px -> 8B store
#pragma unroll
    for (int nt = 0; nt < 4; nt++) {
        int oc = oc0 + wn0 + (nt << 4) + l15;
        float bv = bias[oc - oc0 + oc0];   // bias[oc]
#pragma unroll
        for (int mt = 0; mt < 4; mt++) {
            alignas(8) ushort v4[4];
#pragma unroll
            for (int r = 0; r < 4; r++)
                v4[r] = f2bf(fmaxf(acc[mt][nt][r] + bv, 0.f));
            size_t base = (((size_t)(b * CIN + oc)) << 12) + px0 + wm0 + (mt << 4) + (qd << 2);
            *(u16x4*)&Vw[base] = *(u16x4*)v4;
        }
    }
}

// ---------------------------------------------------------------------------
// MFMA flash attention (unchanged from R2 — verified).
// ---------------------------------------------------------------------------
__global__ __launch_bounds__(512) void flash_mfma(
    const ushort* __restrict__ Q, const ushort* __restrict__ K,
    const ushort* __restrict__ Vt, const float* __restrict__ x1,
    const float* __restrict__ gam, float* __restrict__ out)
{
    const int tid  = threadIdx.x;
    const int lane = tid & 63;
    const int wv   = tid >> 6;
    const int wr   = wv & 1, wc = wv >> 1;
    const int l15  = lane & 15, qd = lane >> 4;

    const int bid   = blockIdx.x;
    const int b     = (bid & 7) >> 1;
    const int itile = ((bid >> 3) << 1) | (bid & 1);
    const int i0    = itile << 6;

    __shared__ alignas(16) ushort Kt[64 * 72];
    __shared__ alignas(16) ushort Vtl[272 * 72];
    __shared__ alignas(16) ushort Pt[64 * 72];
    __shared__ alignas(16) float  redm[4][64];
    __shared__ float lrow[64];

    for (int idx = tid; idx < 16 * 72; idx += 512) {
        int rr = idx / 72;
        Vtl[256 * 72 + idx] = (rr == 0) ? (ushort)0x3F80 : (ushort)0;
    }

    short8 qf[2][2];
#pragma unroll
    for (int it = 0; it < 2; it++)
#pragma unroll
        for (int kb = 0; kb < 2; kb++)
            qf[it][kb] = *(const short8*)(Q +
                (((size_t)(b * HW + i0 + 32 * wr + 16 * it + l15)) << 6) + kb * 32 + qd * 8);

    const floatx4 zv = {0.f, 0.f, 0.f, 0.f};
    floatx4 oa[4][2];
#pragma unroll
    for (int mt = 0; mt < 4; mt++) { oa[mt][0] = zv; oa[mt][1] = zv; }
    floatx4 oa_l[2] = {zv, zv};
    float m_q[2][4], m_l[2];
#pragma unroll
    for (int it = 0; it < 2; it++) {
        m_l[it] = -3.0e38f;
#pragma unroll
        for (int r = 0; r < 4; r++) m_q[it][r] = -3.0e38f;
    }

    for (int j0 = 0; j0 < HW; j0 += 64) {
        __syncthreads();
        {
            int row = tid >> 3, c16 = tid & 7;
            *(short8*)&Kt[row * 72 + c16 * 8] =
                *(const short8*)(K + (((size_t)(b * HW + j0 + row)) << 6) + c16 * 8);
#pragma unroll
            for (int t2 = 0; t2 < 4; t2++) {
                int idx = tid + (t2 << 9);
                int vr = idx >> 3, vc = idx & 7;
                *(short8*)&Vtl[vr * 72 + vc * 8] =
                    *(const short8*)(Vt + (((size_t)(b * CIN + vr)) << 12) + j0 + vc * 8);
            }
        }
        __syncthreads();

        floatx4 s0 = zv, s1 = zv;
#pragma unroll
        for (int kb = 0; kb < 2; kb++) {
            short8 kf = *(short8*)&Kt[(16 * wc + l15) * 72 + kb * 32 + qd * 8];
            s0 = __builtin_amdgcn_mfma_f32_16x16x32_bf16(qf[0][kb], kf, s0, 0, 0, 0);
            s1 = __builtin_amdgcn_mfma_f32_16x16x32_bf16(qf[1][kb], kf, s1, 0, 0, 0);
        }
        float sv[2][4] = {{s0[0], s0[1], s0[2], s0[3]}, {s1[0], s1[1], s1[2], s1[3]}};

        float pm[2][4];
#pragma unroll
        for (int it = 0; it < 2; it++)
#pragma unroll
            for (int r = 0; r < 4; r++) {
                float vx = sv[it][r];
                vx = fmaxf(vx, __shfl_xor(vx, 1));
                vx = fmaxf(vx, __shfl_xor(vx, 2));
                vx = fmaxf(vx, __shfl_xor(vx, 4));
                vx = fmaxf(vx, __shfl_xor(vx, 8));
                pm[it][r] = vx;
            }
        if (l15 == 0) {
#pragma unroll
            for (int it = 0; it < 2; it++)
                *(float4*)&redm[wc][32 * wr + 16 * it + 4 * qd] =
                    make_float4(pm[it][0], pm[it][1], pm[it][2], pm[it][3]);
        }
        __syncthreads();

        float mn_q[2][4], mn_l[2];
#pragma unroll
        for (int it = 0; it < 2; it++) {
            int rq = 32 * wr + 16 * it + 4 * qd;
            float4 a0 = *(float4*)&redm[0][rq];
            float4 a1 = *(float4*)&redm[1][rq];
            float4 a2 = *(float4*)&redm[2][rq];
            float4 a3 = *(float4*)&redm[3][rq];
            mn_q[it][0] = fmaxf(m_q[it][0], fmaxf(fmaxf(a0.x, a1.x), fmaxf(a2.x, a3.x)));
            mn_q[it][1] = fmaxf(m_q[it][1], fmaxf(fmaxf(a0.y, a1.y), fmaxf(a2.y, a3.y)));
            mn_q[it][2] = fmaxf(m_q[it][2], fmaxf(fmaxf(a0.z, a1.z), fmaxf(a2.z, a3.z)));
            mn_q[it][3] = fmaxf(m_q[it][3], fmaxf(fmaxf(a0.w, a1.w), fmaxf(a2.w, a3.w)));
            int rl = 32 * wr + 16 * it + l15;
            mn_l[it] = fmaxf(m_l[it],
                fmaxf(fmaxf(redm[0][rl], redm[1][rl]), fmaxf(redm[2][rl], redm[3][rl])));
        }

#pragma unroll
        for (int it = 0; it < 2; it++)
#pragma unroll
            for (int r = 0; r < 4; r++) {
                float p = exp2f(sv[it][r] - mn_q[it][r]);
                Pt[(32 * wr + 16 * it + 4 * qd + r) * 72 + 16 * wc + l15] = f2bf(p);
                m_q[it][r] = mn_q[it][r];
            }
        __syncthreads();

        float alpha[2];
#pragma unroll
        for (int it = 0; it < 2; it++) {
            alpha[it] = exp2f(m_l[it] - mn_l[it]);
            m_l[it] = mn_l[it];
        }
        if (__any(fminf(alpha[0], alpha[1]) < 1.0f)) {
#pragma unroll
            for (int mt = 0; mt < 4; mt++) {
                oa[mt][0] *= alpha[0];
                oa[mt][1] *= alpha[1];
            }
            oa_l[0] *= alpha[0];
            oa_l[1] *= alpha[1];
        }

#pragma unroll
        for (int kb = 0; kb < 2; kb++) {
            short8 pf0 = *(short8*)&Pt[(32 * wr + l15) * 72 + kb * 32 + qd * 8];
            short8 pf1 = *(short8*)&Pt[(32 * wr + 16 + l15) * 72 + kb * 32 + qd * 8];
#pragma unroll
            for (int mt = 0; mt < 4; mt++) {
                short8 vf = *(short8*)&Vtl[(64 * wc + 16 * mt + l15) * 72 + kb * 32 + qd * 8];
                oa[mt][0] = __builtin_amdgcn_mfma_f32_16x16x32_bf16(vf, pf0, oa[mt][0], 0, 0, 0);
                oa[mt][1] = __builtin_amdgcn_mfma_f32_16x16x32_bf16(vf, pf1, oa[mt][1], 0, 0, 0);
            }
            if (wc == 3) {
                short8 vf = *(short8*)&Vtl[(256 + l15) * 72 + kb * 32 + qd * 8];
                oa_l[0] = __builtin_amdgcn_mfma_f32_16x16x32_bf16(vf, pf0, oa_l[0], 0, 0, 0);
                oa_l[1] = __builtin_amdgcn_mfma_f32_16x16x32_bf16(vf, pf1, oa_l[1], 0, 0, 0);
            }
        }
    }

    __syncthreads();
    if (wc == 3 && qd == 0) {
        lrow[32 * wr + l15]      = oa_l[0][0];
        lrow[32 * wr + 16 + l15] = oa_l[1][0];
    }
    __syncthreads();

    const float gv = gam[0];
#pragma unroll
    for (int it = 0; it < 2; it++) {
        int i = 32 * wr + 16 * it + l15;
        float il = gv / lrow[i];
#pragma unroll
        for (int mt = 0; mt < 4; mt++)
#pragma unroll
            for (int r = 0; r < 4; r++) {
                int c = 64 * wc + 16 * mt + 4 * qd + r;
                size_t idx = (((size_t)(b * CIN + c)) << 12) + i0 + i;
                out[idx] = oa[mt][it][r] * il + x1[idx];
            }
    }
}

// ---------------------------------------------------------------------------
extern "C" void kernel_launch(void* const* d_in, const int* in_sizes, int n_in,
                              void* d_out, int out_size, void* d_ws, size_t ws_size,
                              hipStream_t stream)
{
    const float* x1  = (const float*)d_in[0];
    const float* x2  = (const float*)d_in[1];
    const float* x3  = (const float*)d_in[2];
    const float* w1  = (const float*)d_in[3];
    const float* b1  = (const float*)d_in[4];
    const float* g1  = (const float*)d_in[5];
    const float* be1 = (const float*)d_in[6];
    const float* m1  = (const float*)d_in[7];
    const float* v1  = (const float*)d_in[8];
    const float* w2  = (const float*)d_in[9];
    const float* b2  = (const float*)d_in[10];
    const float* g2  = (const float*)d_in[11];
    const float* be2 = (const float*)d_in[12];
    const float* m2  = (const float*)d_in[13];
    const float* v2  = (const float*)d_in[14];
    const float* w3  = (const float*)d_in[15];
    const float* b3  = (const float*)d_in[16];
    const float* g3  = (const float*)d_in[17];
    const float* be3 = (const float*)d_in[18];
    const float* m3  = (const float*)d_in[19];
    const float* v3  = (const float*)d_in[20];
    const float* gam = (const float*)d_in[21];

    ushort* Xt1 = (ushort*)d_ws;                     // 4M elems, 8 MB
    ushort* Xt2 = Xt1 + (size_t)4194304;
    ushort* Xt3 = Xt2 + (size_t)4194304;
    ushort* Qw  = Xt3 + (size_t)4194304;             // 1M elems, 2 MB
    ushort* Kw  = Qw  + (size_t)1048576;
    ushort* Vw  = Kw  + (size_t)1048576;             // 4M elems, 8 MB
    ushort* w1c = Vw  + (size_t)4194304;
    ushort* w2c = w1c + 16384;
    ushort* w3c = w2c + 16384;
    float*  bc  = (float*)(w3c + 65536);             // 384 floats

    transpose_bf16<<<dim3(64, 4, 12), 256, 0, stream>>>(x1, x2, x3, Xt1, Xt2, Xt3);
    prep_weights<<<385, 256, 0, stream>>>(w1, b1, g1, be1, m1, v1,
                                          w2, b2, g2, be2, m2, v2,
                                          w3, b3, g3, be3, m3, v3,
                                          w1c, w2c, w3c, bc);
    gemm_qk<<<dim3(32, 4, 2), 256, 0, stream>>>(Xt1, Xt2, w1c, w2c, bc, Qw, Kw);
    gemm_v <<<dim3(32, 4, 2), 256, 0, stream>>>(Xt3, w3c, bc, Vw);
    flash_mfma<<<256, 512, 0, stream>>>(Qw, Kw, Vw, x1, gam, (float*)d_out);
}

// Round 4
// 240.229 us; speedup vs baseline: 7.2039x; 1.4101x over previous
//
#include <hip/hip_runtime.h>
#include <math.h>

#define HW 4096
#define CIN 256
#define BN_EPS 1e-5f
#define LOG2E 1.44269504088896f

typedef __attribute__((ext_vector_type(8))) short short8;
typedef __attribute__((ext_vector_type(4))) float floatx4;
typedef __attribute__((ext_vector_type(4))) unsigned short u16x4;
typedef unsigned short ushort;
typedef unsigned int u32;

__device__ inline ushort f2bf(float f) {
    union { float f; unsigned u; } c; c.f = f;
    unsigned r = c.u + 0x7fff + ((c.u >> 16) & 1);   // RNE; inputs are finite
    return (ushort)(r >> 16);
}
__device__ inline float bf2f(ushort u) {
    union { unsigned u; float f; } c; c.u = ((u32)u) << 16; return c.f;
}

// async global->LDS, 16B per lane. LDS dest must be wave-uniform base + lane*16.
__device__ inline void load_lds16(const ushort* g, ushort* l) {
    __builtin_amdgcn_global_load_lds(
        (const __attribute__((address_space(1))) u32*)g,
        (__attribute__((address_space(3))) u32*)l, 16, 0, 0);
}

// ---------------------------------------------------------------------------
// x (fp32, [b][c][hw]) -> Xt (bf16, [b][hw][c])  for all three inputs.
// ---------------------------------------------------------------------------
__global__ __launch_bounds__(256) void transpose_bf16(
    const float* __restrict__ x1, const float* __restrict__ x2,
    const float* __restrict__ x3, ushort* __restrict__ Xt1,
    ushort* __restrict__ Xt2, ushort* __restrict__ Xt3)
{
    const int z = blockIdx.z;
    const int inp = z >> 2, b = z & 3;
    const float* x = inp == 0 ? x1 : (inp == 1 ? x2 : x3);
    ushort* o = inp == 0 ? Xt1 : (inp == 1 ? Xt2 : Xt3);
    const int c0 = blockIdx.y << 6, p0 = blockIdx.x << 6;
    const int tid = threadIdx.x;

    __shared__ float t[64 * 65];

    const int col = tid & 63, r4 = tid >> 6;
#pragma unroll
    for (int t2 = 0; t2 < 16; t2++) {
        int row = (t2 << 2) + r4;
        t[row * 65 + col] = x[((size_t)(b * CIN + c0 + row) << 12) + p0 + col];
    }
    __syncthreads();
    const int p = tid >> 2, cs = (tid & 3) << 4;
    alignas(16) ushort v[16];
#pragma unroll
    for (int k = 0; k < 16; k++) v[k] = f2bf(t[(cs + k) * 65 + p]);
    size_t base = ((size_t)(b * HW + p0 + p)) * 256 + c0 + cs;
    *(short8*)&o[base]     = *(short8*)&v[0];
    *(short8*)&o[base + 8] = *(short8*)&v[8];
}

// ---------------------------------------------------------------------------
// Fold BN into weights/bias, cast weights to bf16.  Q gets log2(e) folded in.
// ---------------------------------------------------------------------------
__global__ __launch_bounds__(256) void prep_weights(
    const float* __restrict__ w1, const float* __restrict__ b1,
    const float* __restrict__ g1, const float* __restrict__ be1,
    const float* __restrict__ m1, const float* __restrict__ v1,
    const float* __restrict__ w2, const float* __restrict__ b2,
    const float* __restrict__ g2, const float* __restrict__ be2,
    const float* __restrict__ m2, const float* __restrict__ v2,
    const float* __restrict__ w3, const float* __restrict__ b3,
    const float* __restrict__ g3, const float* __restrict__ be3,
    const float* __restrict__ m3, const float* __restrict__ v3,
    ushort* __restrict__ w1c, ushort* __restrict__ w2c, ushort* __restrict__ w3c,
    float* __restrict__ bc)
{
    const int bid = blockIdx.x, tid = threadIdx.x;
    if (bid < 384) {
        int idx = bid * 256 + tid;
        if (idx < 16384) {
            int o = idx >> 8;
            float A = g1[o] * rsqrtf(v1[o] + BN_EPS) * LOG2E;
            w1c[idx] = f2bf(w1[idx] * A);
        } else if (idx < 32768) {
            int i2 = idx - 16384, o = i2 >> 8;
            float A = g2[o] * rsqrtf(v2[o] + BN_EPS);
            w2c[i2] = f2bf(w2[i2] * A);
        } else {
            int i3 = idx - 32768, o = i3 >> 8;
            float A = g3[o] * rsqrtf(v3[o] + BN_EPS);
            w3c[i3] = f2bf(w3[i3] * A);
        }
    } else {
        if (tid < 64) {
            float A = g1[tid] * rsqrtf(v1[tid] + BN_EPS);
            bc[tid] = ((b1[tid] - m1[tid]) * A + be1[tid]) * LOG2E;
        } else if (tid < 128) {
            int o = tid - 64;
            float A = g2[o] * rsqrtf(v2[o] + BN_EPS);
            bc[tid] = (b2[o] - m2[o]) * A + be2[o];
        } else {
#pragma unroll
            for (int t = 0; t < 2; t++) {
                int o = (tid - 128) + t * 128;
                float A = g3[o] * rsqrtf(v3[o] + BN_EPS);
                bc[128 + o] = (b3[o] - m3[o]) * A + be3[o];
            }
        }
    }
}

// ---------------------------------------------------------------------------
// Q/K conv GEMM, px-tile 64 -> grid 512 -> 2 blocks/CU.
// ---------------------------------------------------------------------------
__global__ __launch_bounds__(256) void gemm_qk(
    const ushort* __restrict__ Xt1, const ushort* __restrict__ Xt2,
    const ushort* __restrict__ w1c, const ushort* __restrict__ w2c,
    const float* __restrict__ bc, ushort* __restrict__ Qw, ushort* __restrict__ Kw)
{
    const int which = blockIdx.z;
    const ushort* X = which ? Xt2 : Xt1;
    const ushort* W = which ? w2c : w1c;
    const float* bias = bc + which * 64;
    ushort* out = which ? Kw : Qw;
    const int b = blockIdx.y;
    const int px0 = blockIdx.x << 6;

    __shared__ alignas(16) ushort Wl[64 * 64];
    __shared__ alignas(16) ushort Xl[64 * 64];

    const int tid = threadIdx.x;
    const int lane = tid & 63;
    const int wv = tid >> 6;
    const int l15 = lane & 15, qd = lane >> 4;
    const int n0w = wv << 4;
    const int sw = l15 & 7;

    floatx4 acc[4];
#pragma unroll
    for (int mt = 0; mt < 4; mt++) acc[mt] = (floatx4){0.f, 0.f, 0.f, 0.f};

    for (int kk = 0; kk < 4; kk++) {
        const int k0 = kk << 6;
        __syncthreads();
#pragma unroll
        for (int t = 0; t < 2; t++) {
            int L = t * 256 + tid;
            int row = L >> 3, c = L & 7;
            load_lds16(W + row * 256 + k0 + ((c ^ (row & 7)) << 3), Wl + L * 8);
            load_lds16(X + ((size_t)(b * HW + px0 + row)) * 256 + k0 + ((c ^ (row & 7)) << 3),
                       Xl + L * 8);
        }
        __syncthreads();
#pragma unroll
        for (int kb = 0; kb < 2; kb++) {
            const int csel = (((kb << 2) + qd) ^ sw) << 3;
            short8 bfr = *(const short8*)&Xl[((n0w + l15) << 6) + csel];
#pragma unroll
            for (int mt = 0; mt < 4; mt++) {
                short8 af = *(const short8*)&Wl[(((mt << 4) + l15) << 6) + csel];
                acc[mt] = __builtin_amdgcn_mfma_f32_16x16x32_bf16(af, bfr, acc[mt], 0, 0, 0);
            }
        }
    }
    const int px = px0 + n0w + l15;
#pragma unroll
    for (int mt = 0; mt < 4; mt++) {
        alignas(8) ushort v4[4];
#pragma unroll
        for (int r = 0; r < 4; r++) {
            int oc = (mt << 4) + (qd << 2) + r;
            v4[r] = f2bf(fmaxf(acc[mt][r] + bias[oc], 0.f));
        }
        *(u16x4*)&out[(((size_t)(b * HW + px)) << 6) + (mt << 4) + (qd << 2)] = *(u16x4*)v4;
    }
}

// ---------------------------------------------------------------------------
// V conv GEMM, px-tile 64 x oc-tile 128 -> grid 512 -> 2 blocks/CU.
// ---------------------------------------------------------------------------
__global__ __launch_bounds__(256) void gemm_v(
    const ushort* __restrict__ Xt3, const ushort* __restrict__ w3c,
    const float* __restrict__ bc, ushort* __restrict__ Vw)
{
    const int b = blockIdx.y;
    const int px0 = blockIdx.x << 6;
    const int oc0 = blockIdx.z << 7;
    const float* bias = bc + 128;

    __shared__ alignas(16) ushort Xl[64 * 64];
    __shared__ alignas(16) ushort Wl[128 * 64];

    const int tid = threadIdx.x;
    const int lane = tid & 63;
    const int wv = tid >> 6;
    const int l15 = lane & 15, qd = lane >> 4;
    const int wm0 = (wv & 1) << 5, wn0 = (wv >> 1) << 6;
    const int sw = l15 & 7;

    floatx4 acc[2][4];
#pragma unroll
    for (int mt = 0; mt < 2; mt++)
#pragma unroll
        for (int nt = 0; nt < 4; nt++) acc[mt][nt] = (floatx4){0.f, 0.f, 0.f, 0.f};

    for (int kk = 0; kk < 4; kk++) {
        const int k0 = kk << 6;
        __syncthreads();
#pragma unroll
        for (int t = 0; t < 2; t++) {
            int L = t * 256 + tid;
            int row = L >> 3, c = L & 7;
            load_lds16(Xt3 + ((size_t)(b * HW + px0 + row)) * 256 + k0 + ((c ^ (row & 7)) << 3),
                       Xl + L * 8);
        }
#pragma unroll
        for (int t = 0; t < 4; t++) {
            int L = t * 256 + tid;
            int row = L >> 3, c = L & 7;
            load_lds16(w3c + (oc0 + row) * 256 + k0 + ((c ^ (row & 7)) << 3), Wl + L * 8);
        }
        __syncthreads();
#pragma unroll
        for (int kb = 0; kb < 2; kb++) {
            const int csel = (((kb << 2) + qd) ^ sw) << 3;
            short8 af[2], bfr[4];
#pragma unroll
            for (int mt = 0; mt < 2; mt++)
                af[mt] = *(const short8*)&Xl[((wm0 + (mt << 4) + l15) << 6) + csel];
#pragma unroll
            for (int nt = 0; nt < 4; nt++)
                bfr[nt] = *(const short8*)&Wl[((wn0 + (nt << 4) + l15) << 6) + csel];
#pragma unroll
            for (int mt = 0; mt < 2; mt++)
#pragma unroll
                for (int nt = 0; nt < 4; nt++)
                    acc[mt][nt] = __builtin_amdgcn_mfma_f32_16x16x32_bf16(
                        af[mt], bfr[nt], acc[mt][nt], 0, 0, 0);
        }
    }
#pragma unroll
    for (int nt = 0; nt < 4; nt++) {
        int oc = oc0 + wn0 + (nt << 4) + l15;
        float bv = bias[oc];
#pragma unroll
        for (int mt = 0; mt < 2; mt++) {
            alignas(8) ushort v4[4];
#pragma unroll
            for (int r = 0; r < 4; r++)
                v4[r] = f2bf(fmaxf(acc[mt][nt][r] + bv, 0.f));
            size_t base = (((size_t)(b * CIN + oc)) << 12) + px0 + wm0 + (mt << 4) + (qd << 2);
            *(u16x4*)&Vw[base] = *(u16x4*)v4;
        }
    }
}

// ---------------------------------------------------------------------------
// Flash attention, j-split x2.  Block 512 thr = 8 waves: wave (it = w&3 ->
// 16-i tile, ch = w>>2 -> 128-c half).  S^T = mfma(A=K, B=Q) puts i in lanes,
// j in rows -> full-row softmax stats via 2 shfl_xor, no reduction LDS.
// P -> LDS (bf16, swizzled) by ch==0 waves; PV: O^T += V^T P^T.
// Writes bf16 partial O + fp32 m,l per split; merged by merge_out.
// ---------------------------------------------------------------------------
__global__ __launch_bounds__(512, 4) void flash_mfma(
    const ushort* __restrict__ Q, const ushort* __restrict__ K,
    const ushort* __restrict__ Vtg, ushort* __restrict__ Op0,
    ushort* __restrict__ Op1, float* __restrict__ mlM, float* __restrict__ mlL)
{
    const int tid = threadIdx.x;
    const int lane = tid & 63;
    const int wv = tid >> 6;
    const int it = wv & 3, ch = wv >> 2;
    const int l15 = lane & 15, qd = lane >> 4;
    const int sw = l15 & 7;

    const int bid = blockIdx.x;
    const int s = bid >> 8;                  // j-split
    const int r8 = bid & 255;
    const int b = (r8 & 7) >> 1;             // XCD-affine batch
    const int itile = ((r8 >> 3) << 1) | (r8 & 1);
    const int i0 = itile << 6;
    const int jbeg = s << 11;

    __shared__ alignas(16) ushort Kt[64 * 64];    //  8 KB [j][d] swizzled
    __shared__ alignas(16) ushort Vt[256 * 64];   // 32 KB [c][j] swizzled
    __shared__ alignas(16) ushort Pt[64 * 64];    //  8 KB [i][j] swizzled

    const int prow = it * 16 + l15;               // P row = i within tile

    short8 qf[2];
#pragma unroll
    for (int kb = 0; kb < 2; kb++)
        qf[kb] = *(const short8*)(Q + (((size_t)((b << 12) + i0 + prow)) << 6) + kb * 32 + qd * 8);

    const floatx4 zv = {0.f, 0.f, 0.f, 0.f};
    floatx4 acc[8];
#pragma unroll
    for (int ct = 0; ct < 8; ct++) acc[ct] = zv;
    float mrun = -3.0e38f, lrun = 0.f;

    for (int jj = 0; jj < 2048; jj += 64) {
        const int j0 = jbeg + jj;
        __syncthreads();
        {   // stage K (64x64) + V^T (256x64), swizzle on global side, LDS linear
            int row = tid >> 3, cb = tid & 7;
            load_lds16(K + (((size_t)((b << 12) + j0 + row)) << 6) + ((cb ^ (row & 7)) << 3),
                       Kt + tid * 8);
#pragma unroll
            for (int t2 = 0; t2 < 4; t2++) {
                int idx = tid + (t2 << 9);
                int vr = idx >> 3, vc = idx & 7;
                load_lds16(Vtg + (((size_t)(b * CIN + vr)) << 12) + j0 + ((vc ^ (vr & 7)) << 3),
                           Vt + idx * 8);
            }
        }
        __syncthreads();

        // ---- S^T: col = i, row = j.  8 MFMA, 8 K-frag reads.
        floatx4 st[4];
#pragma unroll
        for (int t = 0; t < 4; t++) st[t] = zv;
#pragma unroll
        for (int kb = 0; kb < 2; kb++) {
            const int csel = (((kb << 2) + qd) ^ sw) << 3;
#pragma unroll
            for (int t = 0; t < 4; t++) {
                short8 kf = *(const short8*)&Kt[(((t << 4) + l15) << 6) + csel];
                st[t] = __builtin_amdgcn_mfma_f32_16x16x32_bf16(kf, qf[kb], st[t], 0, 0, 0);
            }
        }

        // ---- in-wave softmax: full 64-j row per lane via 2 shfl_xor
        float mloc = -3.0e38f;
#pragma unroll
        for (int t = 0; t < 4; t++)
#pragma unroll
            for (int r = 0; r < 4; r++) mloc = fmaxf(mloc, st[t][r]);
        mloc = fmaxf(mloc, __shfl_xor(mloc, 16));
        mloc = fmaxf(mloc, __shfl_xor(mloc, 32));
        float mnew = fmaxf(mrun, mloc);

        float rs = 0.f;
#pragma unroll
        for (int t = 0; t < 4; t++)
#pragma unroll
            for (int r = 0; r < 4; r++) {
                float p = exp2f(st[t][r] - mnew);
                st[t][r] = p;
                rs += p;
            }
        rs += __shfl_xor(rs, 16);
        rs += __shfl_xor(rs, 32);
        float alpha = exp2f(mrun - mnew);
        mrun = mnew;
        lrun = lrun * alpha + rs;

        if (ch == 0) {                        // write P rows (disjoint across waves)
#pragma unroll
            for (int t = 0; t < 4; t++) {
                u16x4 pk;
#pragma unroll
                for (int r = 0; r < 4; r++) pk[r] = f2bf(st[t][r]);
                int jb8 = (t << 1) + (qd >> 1);
                *(u16x4*)&Pt[(prow << 6) + (((jb8 ^ sw) << 3) + ((qd & 1) << 2))] = pk;
            }
        }
        __syncthreads();

        if (__any(alpha < 1.0f)) {
#pragma unroll
            for (int ct = 0; ct < 8; ct++) acc[ct] *= alpha;
        }

        // ---- PV: A = V^T c-rows, B = P rows (own i-tile). 16 MFMA, 18 reads.
        short8 pf[2];
#pragma unroll
        for (int kb = 0; kb < 2; kb++)
            pf[kb] = *(const short8*)&Pt[(prow << 6) + ((((kb << 2) + qd) ^ sw) << 3)];
#pragma unroll
        for (int kb = 0; kb < 2; kb++) {
            const int csel = (((kb << 2) + qd) ^ sw) << 3;
#pragma unroll
            for (int ct = 0; ct < 8; ct++) {
                int crow = (ch << 7) + (ct << 4) + l15;
                short8 vf = *(const short8*)&Vt[(crow << 6) + csel];
                acc[ct] = __builtin_amdgcn_mfma_f32_16x16x32_bf16(vf, pf[kb], acc[ct], 0, 0, 0);
            }
        }
    }

    // ---- partial store: Op[s][b][i][c] bf16; m,l per i
    ushort* Op = s ? Op1 : Op0;
    size_t obase = ((size_t)((b << 12) + i0 + prow)) << 8;
#pragma unroll
    for (int ct = 0; ct < 8; ct++) {
        u16x4 pk;
#pragma unroll
        for (int r = 0; r < 4; r++) pk[r] = f2bf(acc[ct][r]);
        *(u16x4*)&Op[obase + (ch << 7) + (ct << 4) + (qd << 2)] = pk;
    }
    if (ch == 0 && qd == 0) {
        int mi = (s << 14) + (b << 12) + i0 + prow;
        mlM[mi] = mrun;
        mlL[mi] = lrun;
    }
}

// ---------------------------------------------------------------------------
// Merge 2 j-split partials + gam/l normalize + residual; [b][i][c]->[b][c][i].
// grid (64 i-tiles, 4 c-tiles, 4 b), 256 thr.
// ---------------------------------------------------------------------------
__global__ __launch_bounds__(256) void merge_out(
    const ushort* __restrict__ Op0, const ushort* __restrict__ Op1,
    const float* __restrict__ mlM, const float* __restrict__ mlL,
    const float* __restrict__ x1, const float* __restrict__ gam,
    float* __restrict__ out)
{
    const int b = blockIdx.z, c0 = blockIdx.y << 6, i0 = blockIdx.x << 6;
    const int tid = threadIdx.x;

    __shared__ float Tl[64][65];
    __shared__ float a0s[64], a1s[64];

    if (tid < 64) {
        int gi = (b << 12) + i0 + tid;
        float m0 = mlM[gi], m1 = mlM[16384 + gi];
        float l0 = mlL[gi], l1 = mlL[16384 + gi];
        float M = fmaxf(m0, m1);
        float w0 = exp2f(m0 - M), w1 = exp2f(m1 - M);
        float gd = gam[0] / (w0 * l0 + w1 * l1);
        a0s[tid] = w0 * gd;
        a1s[tid] = w1 * gd;
    }
    __syncthreads();
#pragma unroll
    for (int k = 0; k < 4; k++) {
        int idx4 = tid + (k << 8);
        int i = idx4 >> 4, c4 = (idx4 & 15) << 2;
        size_t g = ((size_t)((b << 12) + i0 + i)) * 256 + c0 + c4;
        u16x4 p0 = *(const u16x4*)&Op0[g];
        u16x4 p1 = *(const u16x4*)&Op1[g];
        float A0 = a0s[i], A1 = a1s[i];
#pragma unroll
        for (int r = 0; r < 4; r++)
            Tl[c4 + r][i] = A0 * bf2f(p0[r]) + A1 * bf2f(p1[r]);
    }
    __syncthreads();
#pragma unroll
    for (int k = 0; k < 4; k++) {
        int idx4 = tid + (k << 8);
        int c = idx4 >> 4, i4 = (idx4 & 15) << 2;
        size_t g = (((size_t)(b * CIN + c0 + c)) << 12) + i0 + i4;
        float4 xv = *(const float4*)&x1[g];
        float4 o;
        o.x = Tl[c][i4 + 0] + xv.x;
        o.y = Tl[c][i4 + 1] + xv.y;
        o.z = Tl[c][i4 + 2] + xv.z;
        o.w = Tl[c][i4 + 3] + xv.w;
        *(float4*)&out[g] = o;
    }
}

// ---------------------------------------------------------------------------
extern "C" void kernel_launch(void* const* d_in, const int* in_sizes, int n_in,
                              void* d_out, int out_size, void* d_ws, size_t ws_size,
                              hipStream_t stream)
{
    const float* x1  = (const float*)d_in[0];
    const float* x2  = (const float*)d_in[1];
    const float* x3  = (const float*)d_in[2];
    const float* w1  = (const float*)d_in[3];
    const float* b1  = (const float*)d_in[4];
    const float* g1  = (const float*)d_in[5];
    const float* be1 = (const float*)d_in[6];
    const float* m1  = (const float*)d_in[7];
    const float* v1  = (const float*)d_in[8];
    const float* w2  = (const float*)d_in[9];
    const float* b2  = (const float*)d_in[10];
    const float* g2  = (const float*)d_in[11];
    const float* be2 = (const float*)d_in[12];
    const float* m2  = (const float*)d_in[13];
    const float* v2  = (const float*)d_in[14];
    const float* w3  = (const float*)d_in[15];
    const float* b3  = (const float*)d_in[16];
    const float* g3  = (const float*)d_in[17];
    const float* be3 = (const float*)d_in[18];
    const float* m3  = (const float*)d_in[19];
    const float* v3  = (const float*)d_in[20];
    const float* gam = (const float*)d_in[21];

    ushort* Xt1 = (ushort*)d_ws;                     // 4M elems, 8 MB
    ushort* Xt2 = Xt1 + (size_t)4194304;
    ushort* Xt3 = Xt2 + (size_t)4194304;
    ushort* Qw  = Xt3 + (size_t)4194304;             // 1M elems, 2 MB
    ushort* Kw  = Qw  + (size_t)1048576;
    ushort* Vw  = Kw  + (size_t)1048576;             // 4M elems, 8 MB
    ushort* w1c = Vw  + (size_t)4194304;
    ushort* w2c = w1c + 16384;
    ushort* w3c = w2c + 16384;
    float*  bc  = (float*)(w3c + 65536);             // 384 floats

    // dead after the gemms -> reuse for flash partials
    ushort* Op0 = Xt1;                               // 8 MB bf16 [b][i][c]
    ushort* Op1 = Xt2;                               // 8 MB
    float*  mlM = (float*)Xt3;                       // 32768 floats
    float*  mlL = mlM + 32768;

    transpose_bf16<<<dim3(64, 4, 12), 256, 0, stream>>>(x1, x2, x3, Xt1, Xt2, Xt3);
    prep_weights<<<385, 256, 0, stream>>>(w1, b1, g1, be1, m1, v1,
                                          w2, b2, g2, be2, m2, v2,
                                          w3, b3, g3, be3, m3, v3,
                                          w1c, w2c, w3c, bc);
    gemm_qk<<<dim3(64, 4, 2), 256, 0, stream>>>(Xt1, Xt2, w1c, w2c, bc, Qw, Kw);
    gemm_v <<<dim3(64, 4, 2), 256, 0, stream>>>(Xt3, w3c, bc, Vw);
    flash_mfma<<<512, 512, 0, stream>>>(Qw, Kw, Vw, Op0, Op1, mlM, mlL);
    merge_out<<<dim3(64, 4, 4), 256, 0, stream>>>(Op0, Op1, mlM, mlL, x1, gam, (float*)d_out);
}